// Round 10
// baseline (491.066 us; speedup 1.0000x reference)
//
#include <hip/hip_runtime.h>

// M = 9 (lmax=2), NB = 32 channels, NRBF = 20, CUTOFF = 5, T = 2
#define CHUNK 16   // edges per 32-lane group (R8's CHUNK=8 regressed: occupancy+flush)

// ====================== compile-time CG table ======================
constexpr double CFACT[8] = {1.,1.,2.,6.,24.,120.,720.,5040.};

constexpr double csqrt(double x){
  if (x <= 0.0) return 0.0;
  double s = 1.0;
  while (x > 4.0)  { x *= 0.25; s *= 2.0; }
  while (x < 0.25) { x *= 4.0;  s *= 0.5; }
  double g = 1.0;
  for (int i=0;i<10;i++) g = 0.5*(g + x/g);
  return s*g;
}

constexpr double cg_complex(int j1,int m1,int j2,int m2,int j3,int m3){
  if (m3 != m1+m2 || j3 < (j1>j2?j1-j2:j2-j1) || j3 > j1+j2) return 0.0;
  double pref = csqrt((2.0*j3+1.0)*CFACT[j1+j2-j3]*CFACT[j1-j2+j3]*CFACT[-j1+j2+j3]/CFACT[j1+j2+j3+1]);
  pref *= csqrt(CFACT[j1+m1]*CFACT[j1-m1]*CFACT[j2+m2]*CFACT[j2-m2]*CFACT[j3+m3]*CFACT[j3-m3]);
  int kmin = 0;
  if (j2-j3-m1 > kmin) kmin = j2-j3-m1;
  if (j1+m2-j3 > kmin) kmin = j1+m2-j3;
  int kmax = j1+j2-j3;
  if (j1-m1 < kmax) kmax = j1-m1;
  if (j2+m2 < kmax) kmax = j2+m2;
  double s = 0.0;
  for (int k=kmin;k<=kmax;++k){
    double t = 1.0/(CFACT[k]*CFACT[j1+j2-j3-k]*CFACT[j1-m1-k]*CFACT[j2+m2-k]*CFACT[j3-j2+m1+k]*CFACT[j3-j1-m2+k]);
    s += (k&1)? -t : t;
  }
  return pref*s;
}

struct UR { int n; int mc[2]; double re[2]; double im[2]; };
constexpr UR u_row(int m){
  UR u{}; const double is2 = 0.70710678118654752440;
  if (m==0){ u.n=1; u.mc[0]=0; u.re[0]=1.0; u.im[0]=0.0; u.mc[1]=0; u.re[1]=0.0; u.im[1]=0.0; }
  else if (m>0){ u.n=2; u.mc[0]=m;  u.re[0]=((m&1)? -is2:is2); u.im[0]=0.0;
                        u.mc[1]=-m; u.re[1]=is2;               u.im[1]=0.0; }
  else { int mu=-m; u.n=2; u.mc[0]=m;  u.re[0]=0.0; u.im[0]=is2;
                           u.mc[1]=mu; u.re[1]=0.0; u.im[1]=((mu&1)? is2:-is2); }
  return u;
}

struct CGTab { float v[9][9][9]; };
constexpr CGTab build_cg(){
  CGTab g{};
  double cc[9][9][9] = {};
  for (int a=0;a<9;a++){
    int l1 = (a==0)?0:((a<4)?1:2); int m1 = a - (l1*l1+l1);
    for (int b=0;b<9;b++){
      int l2 = (b==0)?0:((b<4)?1:2); int m2 = b - (l2*l2+l2);
      int m3 = m1+m2;
      for (int l3=0;l3<=2;l3++){
        if (m3 < -l3 || m3 > l3) continue;
        cc[a][b][l3*l3+l3+m3] = cg_complex(l1,m1,l2,m2,l3,m3);
      }
    }
  }
  for (int l1=0;l1<=2;l1++) for (int l2=0;l2<=2;l2++) for (int l3=0;l3<=2;l3++){
    if (((l1+l2+l3)&1)==1) continue;
    int dl = (l1>l2)?(l1-l2):(l2-l1);
    if (l3 < dl || l3 > l1+l2) continue;
    for (int m1=-l1;m1<=l1;m1++) for (int m2=-l2;m2<=l2;m2++) for (int m3=-l3;m3<=l3;m3++){
      UR ua = u_row(m1), ub = u_row(m2), uc = u_row(m3);
      double acc = 0.0;
      for (int i=0;i<ua.n;i++) for (int j=0;j<ub.n;j++){
        double zr = ua.re[i]*ub.re[j] - ua.im[i]*ub.im[j];
        double zi = ua.re[i]*ub.im[j] + ua.im[i]*ub.re[j];
        for (int k=0;k<uc.n;k++){
          double rp = zr*uc.re[k] + zi*uc.im[k];   // Re[(za*zb)*conj(zc)]
          if (rp != 0.0)
            acc += rp * cc[l1*l1+l1+ua.mc[i]][l2*l2+l2+ub.mc[j]][l3*l3+l3+uc.mc[k]];
        }
      }
      g.v[l1*l1+l1+m1][l2*l2+l2+m2][l3*l3+l3+m3] = (float)acc;
    }
  }
  return g;
}
constexpr CGTab CGT = build_cg();

// ---------------- edge kernel (exact R7 structure; t0 gathers emb[Z[j]]) ---
// Session ledger (per-edge-dispatch):
//  R0 144 | R2 151 (LDS-bound, model exact) | R3 129 | R4 166 (ILP fail)
//  R5 133+tables (fail) | R6/R7 121 <- plateau, busy ~88us | R8 169 (CHUNK=8:
//  occupancy 28->20% via VGPR 92, atomic WRITE 52->93MB)
// R9: edge untouched (R7-exact, CHUNK=16) except t0 reads emb[Z[j]] directly
// (x is no longer pre-initialized; init kernel removed).
template<bool FIRST>
__global__ __launch_bounds__(256) void edge_kernel(
    const float* __restrict__ r_ij, const int* __restrict__ idx_i, const int* __restrict__ idx_j,
    const float* __restrict__ x, const int* __restrict__ Z, const float* __restrict__ emb,
    const float* __restrict__ Wf_t, const float* __restrict__ bf_t,
    float* __restrict__ dx, int n_edges)
{
  __shared__ __align__(16) float rbs[8][32];   // per-group rb staging
  int tid = threadIdx.x;
  int g = tid >> 5, lane = tid & 31;
  int base = (blockIdx.x*8 + g)*CHUNK;
  if (base >= n_edges) return;
  const int nend = n_edges;

  // per-lane filter weights in registers (reused across all edges)
  float wfr[3][20]; float bfl[3];
  #pragma unroll
  for (int l=0;l<3;l++){
    const float* rp = Wf_t + (l*32+lane)*20;   // 80B rows -> 16B aligned
    #pragma unroll
    for (int q=0;q<5;q++){
      float4 v4 = *reinterpret_cast<const float4*>(rp + q*4);
      wfr[l][q*4+0]=v4.x; wfr[l][q*4+1]=v4.y; wfr[l][q*4+2]=v4.z; wfr[l][q*4+3]=v4.w;
    }
    bfl[l] = bf_t[l*32+lane];
  }

  const float STEP  = 5.0f/19.0f;
  const float ALPHA = -0.5f/(STEP*STEP);
  float myoff = (float)lane * STEP;

  float racc[9];
  #pragma unroll
  for (int c=0;c<9;c++) racc[c]=0.f;
  int cur_i = -1;

  // ---- xj pipeline prologue (depth 1) ----
  float xj[9]; float xj0 = 0.f;
  int zn = 0;
  {
    int j0 = idx_j[base];
    if (FIRST){ xj0 = emb[Z[j0]*32 + lane]; }
    else {
      const float* xp = x + j0*288 + lane;
      #pragma unroll
      for (int b=0;b<9;b++) xj[b] = xp[b*32];
    }
  }
  int e1 = (base+1 <= nend-1) ? base+1 : nend-1;
  int j_next = idx_j[e1];
  if (FIRST) zn = Z[j_next];

  #pragma unroll 2
  for (int k=0;k<CHUNK;k++){
    int e = base + k;
    if (e >= nend) break;              // uniform within the group

    // ---- issue next-edge gathers (consumed next iteration) ----
    float xjn[9]; float xjn0 = 0.f;
    if (FIRST){
      xjn0 = emb[zn*32 + lane];
    } else {
      const float* xp = x + j_next*288 + lane;
      #pragma unroll
      for (int b=0;b<9;b++) xjn[b] = xp[b*32];
    }
    int en2 = (e+2 <= nend-1) ? e+2 : nend-1;
    int j_n2 = idx_j[en2];
    int zn2 = 0;
    if (FIRST) zn2 = Z[j_n2];

    // ---- current edge scalars (group-uniform, L1-hot) ----
    int   ii = idx_i[e];
    float rx = r_ij[3*e+0], ry = r_ij[3*e+1], rz = r_ij[3*e+2];

    // ---- geometry: rsqrt for direction, sqrt for distance (parallel) ----
    float d2 = fmaf(rx,rx,fmaf(ry,ry,rz*rz));
    float inv = __frsqrt_rn(d2);
    float dd = sqrtf(d2);
    float X = rx*inv, Yv = ry*inv, Zv = rz*inv;
    const float c1 = 0.4886025119029199f, c2 = 1.0925484305920792f;
    float Y[9];
    Y[0]=0.28209479177387814f; Y[1]=c1*Yv; Y[2]=c1*Zv; Y[3]=c1*X;
    Y[4]=c2*X*Yv; Y[5]=c2*Yv*Zv; Y[6]=0.31539156525252005f*(3.f*Zv*Zv-1.f);
    Y[7]=c2*X*Zv; Y[8]=0.5462742152960396f*(X*X-Yv*Yv);

    // ---- RBF: lane r computes rb_r; stage via LDS (1 write + 5 b128
    // same-address broadcast reads). Unpredicated write: lanes 20-31 store
    // values that are never read (rbv spans r<20 only). ----
    float dtl = dd - myoff;
    float rbl = __expf(ALPHA*dtl*dtl);
    rbs[g][lane] = rbl;
    __builtin_amdgcn_wave_barrier();      // same-wave ordering; no s_barrier
    float rbv[20];
    {
      const float4* rb4 = reinterpret_cast<const float4*>(&rbs[g][0]);
      #pragma unroll
      for (int q=0;q<5;q++){
        float4 v4 = rb4[q];
        rbv[4*q+0]=v4.x; rbv[4*q+1]=v4.y; rbv[4*q+2]=v4.z; rbv[4*q+3]=v4.w;
      }
    }
    float wl0=bfl[0], wl1=bfl[1], wl2=bfl[2];
    #pragma unroll
    for (int r=0;r<20;r++){
      wl0 = fmaf(rbv[r], wfr[0][r], wl0);
      wl1 = fmaf(rbv[r], wfr[1][r], wl1);
      wl2 = fmaf(rbv[r], wfr[2][r], wl2);
    }
    float fc = (dd < 5.0f) ? 0.5f*(__cosf(dd*0.6283185307179586f)+1.0f) : 0.0f;
    wl0*=fc; wl1*=fc; wl2*=fc;

    if (ii != cur_i){
      if (cur_i >= 0){
        float* dp = dx + cur_i*288 + lane;
        #pragma unroll
        for (int c=0;c<9;c++){ atomicAdd(dp + c*32, racc[c]); racc[c]=0.f; }
      }
      cur_i = ii;
    }

    if (FIRST){
      // yv[c] = Y[c]*xj0 exactly (CG[a][0][c] = delta_ac)
      racc[0] = fmaf(wl0, Y[0]*xj0, racc[0]);
      #pragma unroll
      for (int c=1;c<4;c++) racc[c] = fmaf(wl1, Y[c]*xj0, racc[c]);
      #pragma unroll
      for (int c=4;c<9;c++) racc[c] = fmaf(wl2, Y[c]*xj0, racc[c]);
    } else {
      // yv[c] = sum_{a,b} Y[a] * CG[a][b][c] * xj[b]  (compile-time sparse)
      float yv[9];
      #pragma unroll
      for (int c=0;c<9;c++) yv[c]=0.f;
      #pragma unroll
      for (int a=0;a<9;a++){
        #pragma unroll
        for (int b=0;b<9;b++){
          bool any = false;
          #pragma unroll
          for (int c=0;c<9;c++) any = any | (CGT.v[a][b][c] != 0.f);
          if (any){
            float p = Y[a]*xj[b];
            #pragma unroll
            for (int c=0;c<9;c++){
              if (CGT.v[a][b][c] != 0.f) yv[c] = fmaf(CGT.v[a][b][c], p, yv[c]);
            }
          }
        }
      }
      racc[0] = fmaf(wl0, yv[0], racc[0]);
      #pragma unroll
      for (int c=1;c<4;c++) racc[c] = fmaf(wl1, yv[c], racc[c]);
      #pragma unroll
      for (int c=4;c<9;c++) racc[c] = fmaf(wl2, yv[c], racc[c]);
    }

    // ---- rotate pipeline state ----
    j_next = j_n2;
    if (FIRST){ xj0 = xjn0; zn = zn2; }
    else {
      #pragma unroll
      for (int b=0;b<9;b++) xj[b] = xjn[b];
    }
  }
  if (cur_i >= 0){
    float* dp = dx + cur_i*288 + lane;
    #pragma unroll
    for (int c=0;c<9;c++) atomicAdd(dp + c*32, racc[c]);
  }
}

// ---------------- atom kernel (R9: readlane broadcasts, zero LDS) ----------
// Old structure: 2 atoms/wave64, t-broadcast via LDS tile -> 224 ds_read_b128
// per wave; model: 39 waves/CU x 224 x 12cyc = ~44us/dispatch, LDS-pipe
// bound (matches the 385us accounting gap; atom never in top-5).
// New: ONE atom per wave64; both halves redundantly compute identical
// values (same-addr same-value stores are safe); the n-contraction
// broadcast uses v_readlane with compile-time lane indices -> pure VALU,
// no LDS. Same FP order (n ascending) -> bit-identical results.
__device__ __forceinline__ float rl(float v, int n){
  return __int_as_float(__builtin_amdgcn_readlane(__float_as_int(v), n));
}
__device__ __forceinline__ void load_row(const float* __restrict__ W, int k, float (&wr)[32]){
  const float4* w4 = reinterpret_cast<const float4*>(W + k*32);
  #pragma unroll
  for (int q=0;q<8;q++){ float4 a=w4[q]; wr[4*q]=a.x; wr[4*q+1]=a.y; wr[4*q+2]=a.z; wr[4*q+3]=a.w; }
}

template<bool FIRST_T>
__global__ __launch_bounds__(256) void atom_kernel(
    float* __restrict__ x, float* __restrict__ dxg,
    const int* __restrict__ Z, const float* __restrict__ emb,
    const float* __restrict__ Wm1_t, const float* __restrict__ Wm2_t, const float* __restrict__ Wm3_t,
    const float* __restrict__ Wg_t, const float* __restrict__ bg_t, int n_atoms)
{
  int tid = threadIdx.x;
  int wv = tid >> 6, lane = tid & 63, k = lane & 31;
  int atom = blockIdx.x*4 + wv;
  if (atom >= n_atoms) return;          // wave-uniform

  float* dp = dxg + atom*288 + k;
  float v[9];
  #pragma unroll
  for (int c=0;c<9;c++){ v[c]=dp[c*32]; dp[c*32]=0.f; }   // consume + re-zero

  float wr[32];

  // u = dx @ Wm1^T  (lane k = output channel; broadcast v[c][n] via readlane)
  load_row(Wm1_t, k, wr);
  float u[9];
  #pragma unroll
  for (int c=0;c<9;c++){
    float s=0.f;
    #pragma unroll
    for (int n=0;n<32;n++) s = fmaf(rl(v[c],n), wr[n], s);
    u[c]=s;
  }

  // w = v + CG(v, u)  (compile-time sparse, pointwise in channel)
  float w9[9];
  #pragma unroll
  for (int c=0;c<9;c++) w9[c]=v[c];
  #pragma unroll
  for (int a=0;a<9;a++){
    #pragma unroll
    for (int b=0;b<9;b++){
      bool any = false;
      #pragma unroll
      for (int c=0;c<9;c++) any = any | (CGT.v[a][b][c] != 0.f);
      if (any){
        float p = v[a]*u[b];
        #pragma unroll
        for (int c=0;c<9;c++){
          if (CGT.v[a][b][c] != 0.f) w9[c] = fmaf(CGT.v[a][b][c], p, w9[c]);
        }
      }
    }
  }

  // p = w @ Wm2^T
  load_row(Wm2_t, k, wr);
  float p[9];
  #pragma unroll
  for (int c=0;c<9;c++){
    float s=0.f;
    #pragma unroll
    for (int n=0;n<32;n++) s = fmaf(rl(w9[c],n), wr[n], s);
    p[c]=s;
  }

  // gate from p[0,:]: three rows of Wg, sequential (wr reused)
  float p0 = p[0];
  float h[3];
  #pragma unroll
  for (int l=0;l<3;l++){
    load_row(Wg_t, l*32 + k, wr);
    float s = bg_t[l*32 + k];
    #pragma unroll
    for (int n=0;n<32;n++) s = fmaf(rl(p0,n), wr[n], s);
    h[l] = 1.f/(1.f+__expf(-s));
  }

  float q9[9];
  q9[0]=p[0]*h[0];
  #pragma unroll
  for (int c=1;c<4;c++) q9[c]=p[c]*h[1];
  #pragma unroll
  for (int c=4;c<9;c++) q9[c]=p[c]*h[2];

  // r = q @ Wm3^T ; x update
  load_row(Wm3_t, k, wr);
  float* xo = x + atom*288 + k;
  #pragma unroll
  for (int c=0;c<9;c++){
    float s=0.f;
    #pragma unroll
    for (int n=0;n<32;n++) s = fmaf(rl(q9[c],n), wr[n], s);
    if (FIRST_T){
      // x was never pre-initialized: write init + r (init = emb[Z] on c=0)
      float init = (c==0) ? emb[Z[atom]*32 + k] : 0.f;
      xo[c*32] = init + s;
    } else {
      xo[c*32] += s;      // both halves store identical value: safe
    }
  }
}

// ---------------- launch ----------------
extern "C" void kernel_launch(void* const* d_in, const int* in_sizes, int n_in,
                              void* d_out, int out_size, void* d_ws, size_t ws_size,
                              hipStream_t stream)
{
  const int*   Z    = (const int*)d_in[0];
  const float* r_ij = (const float*)d_in[1];
  const int*   idxi = (const int*)d_in[2];
  const int*   idxj = (const int*)d_in[3];
  const float* emb  = (const float*)d_in[4];
  const float* Wf   = (const float*)d_in[5];
  const float* bf   = (const float*)d_in[6];
  const float* Wm1  = (const float*)d_in[7];
  const float* Wm2  = (const float*)d_in[8];
  const float* Wm3  = (const float*)d_in[9];
  const float* Wg   = (const float*)d_in[10];
  const float* bg   = (const float*)d_in[11];
  int n_atoms = in_sizes[0];
  int n_edges = in_sizes[1]/3;

  float* x  = (float*)d_out;
  float* dx = (float*)d_ws;

  // dx zero via memset (graph-capturable); x needs no init (atom_t0 writes it)
  hipMemsetAsync(dx, 0, (size_t)n_atoms*288*sizeof(float), stream);

  int eblocks = (n_edges + 8*CHUNK - 1)/(8*CHUNK);
  int ablocks = (n_atoms + 3)/4;

  // t = 0 (x sparse: only l=0 row nonzero -> gather emb[Z[j]] directly)
  edge_kernel<true><<<eblocks,256,0,stream>>>(r_ij, idxi, idxj, x, Z, emb, Wf, bf, dx, n_edges);
  atom_kernel<true><<<ablocks,256,0,stream>>>(x, dx, Z, emb, Wm1, Wm2, Wm3, Wg, bg, n_atoms);

  // t = 1 (dense)
  edge_kernel<false><<<eblocks,256,0,stream>>>(r_ij, idxi, idxj, x, Z, emb,
                                        Wf + 96*20, bf + 96, dx, n_edges);
  atom_kernel<false><<<ablocks,256,0,stream>>>(x, dx, Z, emb,
                                        Wm1 + 1024, Wm2 + 1024, Wm3 + 1024,
                                        Wg + 96*32, bg + 96, n_atoms);
}

// Round 11
// 384.305 us; speedup vs baseline: 1.2778x; 1.2778x over previous
//
#include <hip/hip_runtime.h>

// M = 9 (lmax=2), NB = 32 channels, NRBF = 20, CUTOFF = 5, T = 2
#define CHUNK 16   // edges per 32-lane group

// ====================== compile-time CG table ======================
constexpr double CFACT[8] = {1.,1.,2.,6.,24.,120.,720.,5040.};

constexpr double csqrt(double x){
  if (x <= 0.0) return 0.0;
  double s = 1.0;
  while (x > 4.0)  { x *= 0.25; s *= 2.0; }
  while (x < 0.25) { x *= 4.0;  s *= 0.5; }
  double g = 1.0;
  for (int i=0;i<10;i++) g = 0.5*(g + x/g);
  return s*g;
}

constexpr double cg_complex(int j1,int m1,int j2,int m2,int j3,int m3){
  if (m3 != m1+m2 || j3 < (j1>j2?j1-j2:j2-j1) || j3 > j1+j2) return 0.0;
  double pref = csqrt((2.0*j3+1.0)*CFACT[j1+j2-j3]*CFACT[j1-j2+j3]*CFACT[-j1+j2+j3]/CFACT[j1+j2+j3+1]);
  pref *= csqrt(CFACT[j1+m1]*CFACT[j1-m1]*CFACT[j2+m2]*CFACT[j2-m2]*CFACT[j3+m3]*CFACT[j3-m3]);
  int kmin = 0;
  if (j2-j3-m1 > kmin) kmin = j2-j3-m1;
  if (j1+m2-j3 > kmin) kmin = j1+m2-j3;
  int kmax = j1+j2-j3;
  if (j1-m1 < kmax) kmax = j1-m1;
  if (j2+m2 < kmax) kmax = j2+m2;
  double s = 0.0;
  for (int k=kmin;k<=kmax;++k){
    double t = 1.0/(CFACT[k]*CFACT[j1+j2-j3-k]*CFACT[j1-m1-k]*CFACT[j2+m2-k]*CFACT[j3-j2+m1+k]*CFACT[j3-j1-m2+k]);
    s += (k&1)? -t : t;
  }
  return pref*s;
}

struct UR { int n; int mc[2]; double re[2]; double im[2]; };
constexpr UR u_row(int m){
  UR u{}; const double is2 = 0.70710678118654752440;
  if (m==0){ u.n=1; u.mc[0]=0; u.re[0]=1.0; u.im[0]=0.0; u.mc[1]=0; u.re[1]=0.0; u.im[1]=0.0; }
  else if (m>0){ u.n=2; u.mc[0]=m;  u.re[0]=((m&1)? -is2:is2); u.im[0]=0.0;
                        u.mc[1]=-m; u.re[1]=is2;               u.im[1]=0.0; }
  else { int mu=-m; u.n=2; u.mc[0]=m;  u.re[0]=0.0; u.im[0]=is2;
                           u.mc[1]=mu; u.re[1]=0.0; u.im[1]=((mu&1)? is2:-is2); }
  return u;
}

struct CGTab { float v[9][9][9]; };
constexpr CGTab build_cg(){
  CGTab g{};
  double cc[9][9][9] = {};
  for (int a=0;a<9;a++){
    int l1 = (a==0)?0:((a<4)?1:2); int m1 = a - (l1*l1+l1);
    for (int b=0;b<9;b++){
      int l2 = (b==0)?0:((b<4)?1:2); int m2 = b - (l2*l2+l2);
      int m3 = m1+m2;
      for (int l3=0;l3<=2;l3++){
        if (m3 < -l3 || m3 > l3) continue;
        cc[a][b][l3*l3+l3+m3] = cg_complex(l1,m1,l2,m2,l3,m3);
      }
    }
  }
  for (int l1=0;l1<=2;l1++) for (int l2=0;l2<=2;l2++) for (int l3=0;l3<=2;l3++){
    if (((l1+l2+l3)&1)==1) continue;
    int dl = (l1>l2)?(l1-l2):(l2-l1);
    if (l3 < dl || l3 > l1+l2) continue;
    for (int m1=-l1;m1<=l1;m1++) for (int m2=-l2;m2<=l2;m2++) for (int m3=-l3;m3<=l3;m3++){
      UR ua = u_row(m1), ub = u_row(m2), uc = u_row(m3);
      double acc = 0.0;
      for (int i=0;i<ua.n;i++) for (int j=0;j<ub.n;j++){
        double zr = ua.re[i]*ub.re[j] - ua.im[i]*ub.im[j];
        double zi = ua.re[i]*ub.im[j] + ua.im[i]*ub.re[j];
        for (int k=0;k<uc.n;k++){
          double rp = zr*uc.re[k] + zi*uc.im[k];   // Re[(za*zb)*conj(zc)]
          if (rp != 0.0)
            acc += rp * cc[l1*l1+l1+ua.mc[i]][l2*l2+l2+ub.mc[j]][l3*l3+l3+uc.mc[k]];
        }
      }
      g.v[l1*l1+l1+m1][l2*l2+l2+m2][l3*l3+l3+m3] = (float)acc;
    }
  }
  return g;
}
constexpr CGTab CGT = build_cg();

// ---------------- edge kernel ----------------
// Session ledger (per-edge-dispatch):
//  R0 144 | R2 151 (LDS-bound) | R3 129 | R4 166 (ILP fail) | R5 133+tables
//  R6/R7 121 (busy ~88us, stall ~33us) | R8 169 (CHUNK=8 fail)
//  R9/R10 atom-readlane fail (123us atom; broadcasts via LDS b128 >> readlane)
// R11 edge: R7-exact + depth-1 prefetch of idx_i/r_ij (the one load chain
// that was never pipelined — consumed same-iteration since R3; suspected
// source of the 33us stall affecting both variants equally). t0 gathers
// emb[Z[j]] directly (x not pre-initialized; init kernel removed, R10-verified).
template<bool FIRST>
__global__ __launch_bounds__(256) void edge_kernel(
    const float* __restrict__ r_ij, const int* __restrict__ idx_i, const int* __restrict__ idx_j,
    const float* __restrict__ x, const int* __restrict__ Z, const float* __restrict__ emb,
    const float* __restrict__ Wf_t, const float* __restrict__ bf_t,
    float* __restrict__ dx, int n_edges)
{
  __shared__ __align__(16) float rbs[8][32];   // per-group rb staging
  int tid = threadIdx.x;
  int g = tid >> 5, lane = tid & 31;
  int base = (blockIdx.x*8 + g)*CHUNK;
  if (base >= n_edges) return;
  const int nend = n_edges;

  // per-lane filter weights in registers (reused across all edges)
  float wfr[3][20]; float bfl[3];
  #pragma unroll
  for (int l=0;l<3;l++){
    const float* rp = Wf_t + (l*32+lane)*20;   // 80B rows -> 16B aligned
    #pragma unroll
    for (int q=0;q<5;q++){
      float4 v4 = *reinterpret_cast<const float4*>(rp + q*4);
      wfr[l][q*4+0]=v4.x; wfr[l][q*4+1]=v4.y; wfr[l][q*4+2]=v4.z; wfr[l][q*4+3]=v4.w;
    }
    bfl[l] = bf_t[l*32+lane];
  }

  const float STEP  = 5.0f/19.0f;
  const float ALPHA = -0.5f/(STEP*STEP);
  float myoff = (float)lane * STEP;

  float racc[9];
  #pragma unroll
  for (int c=0;c<9;c++) racc[c]=0.f;
  int cur_i = -1;

  // ---- pipeline prologue (depth 1 on ALL per-edge streams) ----
  // current-edge scalars:
  int   ii_c = idx_i[base];
  float rx = r_ij[3*base+0], ry = r_ij[3*base+1], rz = r_ij[3*base+2];
  // current-edge xj:
  float xj[9]; float xj0 = 0.f;
  int zn = 0;
  {
    int j0 = idx_j[base];
    if (FIRST){ xj0 = emb[Z[j0]*32 + lane]; }
    else {
      const float* xp = x + j0*288 + lane;
      #pragma unroll
      for (int b=0;b<9;b++) xj[b] = xp[b*32];
    }
  }
  int e1 = (base+1 <= nend-1) ? base+1 : nend-1;
  int j_next = idx_j[e1];
  if (FIRST) zn = Z[j_next];

  #pragma unroll 2
  for (int k=0;k<CHUNK;k++){
    int e = base + k;
    if (e >= nend) break;              // uniform within the group

    // ---- issue loads for edge e+1 (consumed next iteration) ----
    int en = (e+1 <= nend-1) ? e+1 : nend-1;
    int   ii_n = idx_i[en];
    float rxn = r_ij[3*en+0], ryn = r_ij[3*en+1], rzn = r_ij[3*en+2];
    float xjn[9]; float xjn0 = 0.f;
    if (FIRST){
      xjn0 = emb[zn*32 + lane];
    } else {
      const float* xp = x + j_next*288 + lane;
      #pragma unroll
      for (int b=0;b<9;b++) xjn[b] = xp[b*32];
    }
    int en2 = (e+2 <= nend-1) ? e+2 : nend-1;
    int j_n2 = idx_j[en2];
    int zn2 = 0;
    if (FIRST) zn2 = Z[j_n2];

    // ---- geometry: rsqrt for direction, sqrt for distance (parallel) ----
    float d2 = fmaf(rx,rx,fmaf(ry,ry,rz*rz));
    float inv = __frsqrt_rn(d2);
    float dd = sqrtf(d2);
    float X = rx*inv, Yv = ry*inv, Zv = rz*inv;
    const float c1 = 0.4886025119029199f, c2 = 1.0925484305920792f;
    float Y[9];
    Y[0]=0.28209479177387814f; Y[1]=c1*Yv; Y[2]=c1*Zv; Y[3]=c1*X;
    Y[4]=c2*X*Yv; Y[5]=c2*Yv*Zv; Y[6]=0.31539156525252005f*(3.f*Zv*Zv-1.f);
    Y[7]=c2*X*Zv; Y[8]=0.5462742152960396f*(X*X-Yv*Yv);

    // ---- RBF: lane r computes rb_r; stage via LDS (1 write + 5 b128
    // same-address broadcast reads; conflict-free). Unpredicated write:
    // lanes 20-31 store values never read (rbv spans r<20 only). ----
    float dtl = dd - myoff;
    float rbl = __expf(ALPHA*dtl*dtl);
    rbs[g][lane] = rbl;
    __builtin_amdgcn_wave_barrier();      // same-wave ordering; no s_barrier
    float rbv[20];
    {
      const float4* rb4 = reinterpret_cast<const float4*>(&rbs[g][0]);
      #pragma unroll
      for (int q=0;q<5;q++){
        float4 v4 = rb4[q];
        rbv[4*q+0]=v4.x; rbv[4*q+1]=v4.y; rbv[4*q+2]=v4.z; rbv[4*q+3]=v4.w;
      }
    }
    float wl0=bfl[0], wl1=bfl[1], wl2=bfl[2];
    #pragma unroll
    for (int r=0;r<20;r++){
      wl0 = fmaf(rbv[r], wfr[0][r], wl0);
      wl1 = fmaf(rbv[r], wfr[1][r], wl1);
      wl2 = fmaf(rbv[r], wfr[2][r], wl2);
    }
    float fc = (dd < 5.0f) ? 0.5f*(__cosf(dd*0.6283185307179586f)+1.0f) : 0.0f;
    wl0*=fc; wl1*=fc; wl2*=fc;

    if (ii_c != cur_i){
      if (cur_i >= 0){
        float* dp = dx + cur_i*288 + lane;
        #pragma unroll
        for (int c=0;c<9;c++){ atomicAdd(dp + c*32, racc[c]); racc[c]=0.f; }
      }
      cur_i = ii_c;
    }

    if (FIRST){
      // yv[c] = Y[c]*xj0 exactly (CG[a][0][c] = delta_ac)
      racc[0] = fmaf(wl0, Y[0]*xj0, racc[0]);
      #pragma unroll
      for (int c=1;c<4;c++) racc[c] = fmaf(wl1, Y[c]*xj0, racc[c]);
      #pragma unroll
      for (int c=4;c<9;c++) racc[c] = fmaf(wl2, Y[c]*xj0, racc[c]);
    } else {
      // yv[c] = sum_{a,b} Y[a] * CG[a][b][c] * xj[b]  (compile-time sparse)
      float yv[9];
      #pragma unroll
      for (int c=0;c<9;c++) yv[c]=0.f;
      #pragma unroll
      for (int a=0;a<9;a++){
        #pragma unroll
        for (int b=0;b<9;b++){
          bool any = false;
          #pragma unroll
          for (int c=0;c<9;c++) any = any | (CGT.v[a][b][c] != 0.f);
          if (any){
            float p = Y[a]*xj[b];
            #pragma unroll
            for (int c=0;c<9;c++){
              if (CGT.v[a][b][c] != 0.f) yv[c] = fmaf(CGT.v[a][b][c], p, yv[c]);
            }
          }
        }
      }
      racc[0] = fmaf(wl0, yv[0], racc[0]);
      #pragma unroll
      for (int c=1;c<4;c++) racc[c] = fmaf(wl1, yv[c], racc[c]);
      #pragma unroll
      for (int c=4;c<9;c++) racc[c] = fmaf(wl2, yv[c], racc[c]);
    }

    // ---- rotate pipeline state ----
    ii_c = ii_n; rx = rxn; ry = ryn; rz = rzn;
    j_next = j_n2;
    if (FIRST){ xj0 = xjn0; zn = zn2; }
    else {
      #pragma unroll
      for (int b=0;b<9;b++) xj[b] = xjn[b];
    }
  }
  if (cur_i >= 0){
    float* dp = dx + cur_i*288 + lane;
    #pragma unroll
    for (int c=0;c<9;c++) atomicAdd(dp + c*32, racc[c]);
  }
}

// ---------------- atom kernel (R7-verified LDS-tile structure) ----------
// 2 atoms/wave64 (8/block): t-broadcasts via same-address ds_read_b128
// (4 values/instr, conflict-free) — measured far cheaper than readlane
// (R10: readlane atom = 123us vs this ~66us). FIRST_T folds x-init
// (x = emb-init + r) so no init kernel is needed.
template<bool FIRST_T>
__global__ __launch_bounds__(256) void atom_kernel(
    float* __restrict__ x, float* __restrict__ dxg,
    const int* __restrict__ Z, const float* __restrict__ emb,
    const float* __restrict__ Wm1_t, const float* __restrict__ Wm2_t, const float* __restrict__ Wm3_t,
    const float* __restrict__ Wg_t, const float* __restrict__ bg_t, int n_atoms)
{
  __shared__ __align__(16) float tile[8][288];
  int tid = threadIdx.x;
  int g = tid>>5, k = tid&31;
  int atom = blockIdx.x*8 + g;
  if (atom >= n_atoms) return;
  float* tg = &tile[g][0];
  const float4* t4 = reinterpret_cast<const float4*>(tg);

  float* dp = dxg + atom*288 + k;
  float v[9];
  #pragma unroll
  for (int c=0;c<9;c++){ v[c]=dp[c*32]; tg[c*32+k]=v[c]; dp[c*32]=0.f; }  // consume + re-zero

  // u = dx @ Wm1^T   (lane k = output channel; row k of Wm1 is contiguous)
  float wr[32];
  {
    const float4* w4 = reinterpret_cast<const float4*>(Wm1_t + k*32);
    #pragma unroll
    for (int q=0;q<8;q++){ float4 a=w4[q]; wr[4*q]=a.x; wr[4*q+1]=a.y; wr[4*q+2]=a.z; wr[4*q+3]=a.w; }
  }
  float u[9];
  #pragma unroll
  for (int c=0;c<9;c++){
    float s=0.f;
    #pragma unroll
    for (int q=0;q<8;q++){
      float4 tv = t4[c*8+q];
      s = fmaf(tv.x, wr[4*q+0], s); s = fmaf(tv.y, wr[4*q+1], s);
      s = fmaf(tv.z, wr[4*q+2], s); s = fmaf(tv.w, wr[4*q+3], s);
    }
    u[c]=s;
  }

  // w = v + CG(v,u)  (compile-time sparse, pointwise in channel)
  float w[9];
  #pragma unroll
  for (int c=0;c<9;c++) w[c]=v[c];
  #pragma unroll
  for (int a=0;a<9;a++){
    #pragma unroll
    for (int b=0;b<9;b++){
      bool any = false;
      #pragma unroll
      for (int c=0;c<9;c++) any = any | (CGT.v[a][b][c] != 0.f);
      if (any){
        float p = v[a]*u[b];
        #pragma unroll
        for (int c=0;c<9;c++){
          if (CGT.v[a][b][c] != 0.f) w[c] = fmaf(CGT.v[a][b][c], p, w[c]);
        }
      }
    }
  }

  // p = w @ Wm2^T
  #pragma unroll
  for (int c=0;c<9;c++) tg[c*32+k]=w[c];
  {
    const float4* w4 = reinterpret_cast<const float4*>(Wm2_t + k*32);
    #pragma unroll
    for (int q=0;q<8;q++){ float4 a=w4[q]; wr[4*q]=a.x; wr[4*q+1]=a.y; wr[4*q+2]=a.z; wr[4*q+3]=a.w; }
  }
  float p[9];
  #pragma unroll
  for (int c=0;c<9;c++){
    float s=0.f;
    #pragma unroll
    for (int q=0;q<8;q++){
      float4 tv = t4[c*8+q];
      s = fmaf(tv.x, wr[4*q+0], s); s = fmaf(tv.y, wr[4*q+1], s);
      s = fmaf(tv.z, wr[4*q+2], s); s = fmaf(tv.w, wr[4*q+3], s);
    }
    p[c]=s;
  }

  // gate from p[0,:]: lane k needs rows k, 32+k, 64+k of Wg (contiguous)
  tg[k] = p[0];
  float s0=bg_t[k], s1=bg_t[32+k], s2=bg_t[64+k];
  {
    const float4* wg0 = reinterpret_cast<const float4*>(Wg_t + (     k)*32);
    const float4* wg1 = reinterpret_cast<const float4*>(Wg_t + (32 + k)*32);
    const float4* wg2 = reinterpret_cast<const float4*>(Wg_t + (64 + k)*32);
    #pragma unroll
    for (int q=0;q<8;q++){
      float4 tv = t4[q];
      float4 a0 = wg0[q], a1 = wg1[q], a2 = wg2[q];
      s0 = fmaf(tv.x,a0.x,s0); s0 = fmaf(tv.y,a0.y,s0); s0 = fmaf(tv.z,a0.z,s0); s0 = fmaf(tv.w,a0.w,s0);
      s1 = fmaf(tv.x,a1.x,s1); s1 = fmaf(tv.y,a1.y,s1); s1 = fmaf(tv.z,a1.z,s1); s1 = fmaf(tv.w,a1.w,s1);
      s2 = fmaf(tv.x,a2.x,s2); s2 = fmaf(tv.y,a2.y,s2); s2 = fmaf(tv.z,a2.z,s2); s2 = fmaf(tv.w,a2.w,s2);
    }
  }
  float h0 = 1.f/(1.f+__expf(-s0));
  float h1 = 1.f/(1.f+__expf(-s1));
  float h2 = 1.f/(1.f+__expf(-s2));

  float q9[9];
  q9[0]=p[0]*h0;
  #pragma unroll
  for (int c=1;c<4;c++) q9[c]=p[c]*h1;
  #pragma unroll
  for (int c=4;c<9;c++) q9[c]=p[c]*h2;

  // r = q @ Wm3^T ; x update
  #pragma unroll
  for (int c=0;c<9;c++) tg[c*32+k]=q9[c];
  {
    const float4* w4 = reinterpret_cast<const float4*>(Wm3_t + k*32);
    #pragma unroll
    for (int q=0;q<8;q++){ float4 a=w4[q]; wr[4*q]=a.x; wr[4*q+1]=a.y; wr[4*q+2]=a.z; wr[4*q+3]=a.w; }
  }
  float* xo = x + atom*288 + k;
  #pragma unroll
  for (int c=0;c<9;c++){
    float s=0.f;
    #pragma unroll
    for (int q=0;q<8;q++){
      float4 tv = t4[c*8+q];
      s = fmaf(tv.x, wr[4*q+0], s); s = fmaf(tv.y, wr[4*q+1], s);
      s = fmaf(tv.z, wr[4*q+2], s); s = fmaf(tv.w, wr[4*q+3], s);
    }
    if (FIRST_T){
      float init = (c==0) ? emb[Z[atom]*32 + k] : 0.f;
      xo[c*32] = init + s;          // x never pre-initialized
    } else {
      xo[c*32] += s;
    }
  }
}

// ---------------- launch ----------------
extern "C" void kernel_launch(void* const* d_in, const int* in_sizes, int n_in,
                              void* d_out, int out_size, void* d_ws, size_t ws_size,
                              hipStream_t stream)
{
  const int*   Z    = (const int*)d_in[0];
  const float* r_ij = (const float*)d_in[1];
  const int*   idxi = (const int*)d_in[2];
  const int*   idxj = (const int*)d_in[3];
  const float* emb  = (const float*)d_in[4];
  const float* Wf   = (const float*)d_in[5];
  const float* bf   = (const float*)d_in[6];
  const float* Wm1  = (const float*)d_in[7];
  const float* Wm2  = (const float*)d_in[8];
  const float* Wm3  = (const float*)d_in[9];
  const float* Wg   = (const float*)d_in[10];
  const float* bg   = (const float*)d_in[11];
  int n_atoms = in_sizes[0];
  int n_edges = in_sizes[1]/3;

  float* x  = (float*)d_out;
  float* dx = (float*)d_ws;

  // dx zero via memset (graph-capturable); x needs no init (atom_t0 writes it)
  hipMemsetAsync(dx, 0, (size_t)n_atoms*288*sizeof(float), stream);

  int eblocks = (n_edges + 8*CHUNK - 1)/(8*CHUNK);
  int ablocks = (n_atoms + 7)/8;

  // t = 0 (x sparse: only l=0 row nonzero -> gather emb[Z[j]] directly)
  edge_kernel<true><<<eblocks,256,0,stream>>>(r_ij, idxi, idxj, x, Z, emb, Wf, bf, dx, n_edges);
  atom_kernel<true><<<ablocks,256,0,stream>>>(x, dx, Z, emb, Wm1, Wm2, Wm3, Wg, bg, n_atoms);

  // t = 1 (dense)
  edge_kernel<false><<<eblocks,256,0,stream>>>(r_ij, idxi, idxj, x, Z, emb,
                                        Wf + 96*20, bf + 96, dx, n_edges);
  atom_kernel<false><<<ablocks,256,0,stream>>>(x, dx, Z, emb,
                                        Wm1 + 1024, Wm2 + 1024, Wm3 + 1024,
                                        Wg + 96*32, bg + 96, n_atoms);
}